// Round 1
// baseline (252.985 us; speedup 1.0000x reference)
//
#include <hip/hip_runtime.h>

// ---------------------------------------------------------------------------
// T5 cross-attention fused pipeline for MI355X (gfx950)
// B=2, Q=KV=2048, D_MODEL=1024, H=16, D=64
// ---------------------------------------------------------------------------

typedef __attribute__((ext_vector_type(8))) short  s16x8;   // 8 bf16 (A/B frag)
typedef __attribute__((ext_vector_type(4))) float  f32x4;   // C/D frag

__device__ __forceinline__ unsigned short f2bf(float f) {
  unsigned int u = __builtin_bit_cast(unsigned int, f);
  return (unsigned short)((u + 0x7FFFu + ((u >> 16) & 1u)) >> 16);  // RNE
}

__device__ __forceinline__ void gload16(const void* g, void* l) {
  __builtin_amdgcn_global_load_lds(
      (const __attribute__((address_space(1))) unsigned int*)g,
      (__attribute__((address_space(3))) unsigned int*)l, 16, 0, 0);
}

// ---------------------------------------------------------------------------
// Transpose-cast: out[n][k] = bf16(in[k][n]), 1024x1024 f32 -> bf16
// ---------------------------------------------------------------------------
__global__ __launch_bounds__(256) void k_transpose_cast(
    const float* __restrict__ in, unsigned short* __restrict__ out) {
  __shared__ float tile[64][65];
  int t = threadIdx.x;
  int tx = t & 15, ty = t >> 4;
  int r0 = blockIdx.y * 64, c0 = blockIdx.x * 64;
#pragma unroll
  for (int p = 0; p < 4; ++p) {
    int r = p * 16 + ty;
    float4 v = *reinterpret_cast<const float4*>(in + (size_t)(r0 + r) * 1024 + c0 + tx * 4);
    tile[r][tx * 4 + 0] = v.x; tile[r][tx * 4 + 1] = v.y;
    tile[r][tx * 4 + 2] = v.z; tile[r][tx * 4 + 3] = v.w;
  }
  __syncthreads();
#pragma unroll
  for (int p = 0; p < 4; ++p) {
    int c = p * 16 + ty;  // local n index
    unsigned int lo = (unsigned int)f2bf(tile[tx * 4 + 0][c]) |
                      ((unsigned int)f2bf(tile[tx * 4 + 1][c]) << 16);
    unsigned int hi = (unsigned int)f2bf(tile[tx * 4 + 2][c]) |
                      ((unsigned int)f2bf(tile[tx * 4 + 3][c]) << 16);
    uint2 pk; pk.x = lo; pk.y = hi;
    *reinterpret_cast<uint2*>(out + (size_t)(c0 + c) * 1024 + r0 + tx * 4) = pk;
  }
}

// ---------------------------------------------------------------------------
// RMSNorm (T5-style) + cast to bf16. One block per row of 1024.
// ---------------------------------------------------------------------------
__global__ __launch_bounds__(256) void k_rmsnorm(
    const float* __restrict__ hs, const float* __restrict__ w,
    unsigned short* __restrict__ out) {
  int row = blockIdx.x, t = threadIdx.x;
  float4 v = *reinterpret_cast<const float4*>(hs + (size_t)row * 1024 + t * 4);
  float s = v.x * v.x + v.y * v.y + v.z * v.z + v.w * v.w;
#pragma unroll
  for (int m = 1; m < 64; m <<= 1) s += __shfl_xor(s, m);
  __shared__ float ps[4];
  if ((t & 63) == 0) ps[t >> 6] = s;
  __syncthreads();
  float tot = ps[0] + ps[1] + ps[2] + ps[3];
  float sc = rsqrtf(tot * (1.0f / 1024.0f) + 1e-6f);
  float4 wv = *reinterpret_cast<const float4*>(w + t * 4);
  unsigned int lo = (unsigned int)f2bf(v.x * sc * wv.x) |
                    ((unsigned int)f2bf(v.y * sc * wv.y) << 16);
  unsigned int hi = (unsigned int)f2bf(v.z * sc * wv.z) |
                    ((unsigned int)f2bf(v.w * sc * wv.w) << 16);
  uint2 pk; pk.x = lo; pk.y = hi;
  *reinterpret_cast<uint2*>(out + (size_t)row * 1024 + t * 4) = pk;
}

// ---------------------------------------------------------------------------
// Plain f32 -> bf16 cast (vectorized, grid-stride over float4 groups)
// ---------------------------------------------------------------------------
__global__ __launch_bounds__(256) void k_cast(
    const float* __restrict__ in, unsigned short* __restrict__ out, int n4) {
  int i = blockIdx.x * 256 + threadIdx.x;
  int stride = gridDim.x * 256;
  for (; i < n4; i += stride) {
    float4 v = *reinterpret_cast<const float4*>(in + (size_t)i * 4);
    unsigned int lo = (unsigned int)f2bf(v.x) | ((unsigned int)f2bf(v.y) << 16);
    unsigned int hi = (unsigned int)f2bf(v.z) | ((unsigned int)f2bf(v.w) << 16);
    uint2 pk; pk.x = lo; pk.y = hi;
    *reinterpret_cast<uint2*>(out + (size_t)i * 4) = pk;
  }
}

// ---------------------------------------------------------------------------
// GEMM C[M,N] = A[M,K] * Bt[N,K]^T   (M=4096, N=1024, K=1024, bf16 in)
// 128x128 tile, BK=32, 4 waves (2x2), global_load_lds staging (m97 structure)
// MODE 0: bf16 out [M][1024]
// MODE 1: bf16 out transposed to vT layout [b][h][d][2048]  (for V)
// MODE 2: f32 out + residual add (final projection)
// ---------------------------------------------------------------------------
template <int MODE>
__global__ __launch_bounds__(256) void k_gemm(
    const unsigned short* __restrict__ A, const unsigned short* __restrict__ Bt,
    void* __restrict__ Cout, const float* __restrict__ resid) {
  __shared__ __align__(16) char sm[16384];
  char* As = sm;
  char* Bs = sm + 8192;
  int t = threadIdx.x;
  int bn = blockIdx.x, bm = blockIdx.y;
  int m0 = bm * 128, n0 = bn * 128;
  int lane = t & 63, w = t >> 6, lr = lane & 15, lg = lane >> 4;
  int wr = w >> 1, wc = w & 1;

  f32x4 acc[4][4] = {};

  const unsigned short* aA = A + (size_t)(m0 + (t >> 2)) * 1024 + (t & 3) * 8;
  const unsigned short* aB = Bt + (size_t)(n0 + (t >> 2)) * 1024 + (t & 3) * 8;

  for (int kt = 0; kt < 32; ++kt) {
    int k0 = kt * 32;
    gload16(aA + k0,             As + t * 16);
    gload16(aA + 64 * 1024 + k0, As + 4096 + t * 16);
    gload16(aB + k0,             Bs + t * 16);
    gload16(aB + 64 * 1024 + k0, Bs + 4096 + t * 16);
    __syncthreads();
    s16x8 af[4], bf[4];
#pragma unroll
    for (int m = 0; m < 4; ++m)
      af[m] = *reinterpret_cast<const s16x8*>(As + (wr * 64 + m * 16 + lr) * 64 + lg * 16);
#pragma unroll
    for (int n = 0; n < 4; ++n)
      bf[n] = *reinterpret_cast<const s16x8*>(Bs + (wc * 64 + n * 16 + lr) * 64 + lg * 16);
#pragma unroll
    for (int m = 0; m < 4; ++m)
#pragma unroll
      for (int n = 0; n < 4; ++n)
        acc[m][n] = __builtin_amdgcn_mfma_f32_16x16x32_bf16(af[m], bf[n], acc[m][n], 0, 0, 0);
    __syncthreads();
  }

#pragma unroll
  for (int m = 0; m < 4; ++m)
#pragma unroll
    for (int n = 0; n < 4; ++n) {
      int colg = n0 + wc * 64 + n * 16 + lr;
      int rowb = m0 + wr * 64 + m * 16 + lg * 4;
      if (MODE == 0) {
        unsigned short* C = (unsigned short*)Cout;
#pragma unroll
        for (int r = 0; r < 4; ++r)
          C[(size_t)(rowb + r) * 1024 + colg] = f2bf(acc[m][n][r]);
      } else if (MODE == 1) {
        // transposed: vT[((b*16+h)*64+d)][kv], 4 consecutive kv per frag
        int h = colg >> 6, d = colg & 63;
        int b = rowb >> 11, kv = rowb & 2047;
        unsigned short* C = (unsigned short*)Cout +
            ((size_t)((b * 16 + h) * 64 + d) * 2048 + kv);
        unsigned int lo = (unsigned int)f2bf(acc[m][n][0]) |
                          ((unsigned int)f2bf(acc[m][n][1]) << 16);
        unsigned int hi = (unsigned int)f2bf(acc[m][n][2]) |
                          ((unsigned int)f2bf(acc[m][n][3]) << 16);
        uint2 pk; pk.x = lo; pk.y = hi;
        *reinterpret_cast<uint2*>(C) = pk;
      } else {
        float* C = (float*)Cout;
#pragma unroll
        for (int r = 0; r < 4; ++r) {
          size_t idx = (size_t)(rowb + r) * 1024 + colg;
          C[idx] = resid[idx] + acc[m][n][r];
        }
      }
    }
}

// ---------------------------------------------------------------------------
// Flash attention. Grid: (16 q-tiles, 32 b*h). Block: 256 thr = 4 waves.
// Each wave owns 32 q-rows; KV tiles of 128; online softmax wave-local.
// q,k layout [b*2048+pos][h*64+d] bf16; vt layout [(b*16+h)*64+d][2048] bf16.
// LDS (64KB): Ks[128][64] swz | Vs[64][128] swz | Ps[4][32][128] swz (Q staged
// into first 16KB of Ps before the loop).
// ---------------------------------------------------------------------------
__global__ __launch_bounds__(256) void k_attn(
    const unsigned short* __restrict__ q, const unsigned short* __restrict__ k,
    const unsigned short* __restrict__ vt, unsigned short* __restrict__ ctx) {
  __shared__ __align__(16) char sm[65536];
  char* Ks = sm;            // 16 KB
  char* Vs = sm + 16384;    // 16 KB
  char* Ps = sm + 32768;    // 32 KB (also Q staging area)
  int t = threadIdx.x, w = t >> 6, lane = t & 63, lr = lane & 15, lg = lane >> 4;
  int qt = blockIdx.x, bh = blockIdx.y, b = bh >> 4, h = bh & 15;

  const unsigned short* qp = q + (size_t)(b * 2048 + qt * 128) * 1024 + h * 64;
  const unsigned short* kp = k + (size_t)(b * 2048) * 1024 + h * 64;
  const unsigned short* vp = vt + (size_t)(bh * 64) * 2048;

  // ---- stage Q [128][64] (swizzled) into Ps area
  {
    int row = t >> 3, cb = (t & 7) * 16;
#pragma unroll
    for (int i = 0; i < 4; ++i) {
      int r = i * 32 + row;
      int4 v = *reinterpret_cast<const int4*>(qp + (size_t)r * 1024 + (t & 7) * 8);
      *reinterpret_cast<int4*>(Ps + ((r * 128 + cb) ^ ((r & 7) << 4))) = v;
    }
  }
  __syncthreads();
  s16x8 qa[2][2];
#pragma unroll
  for (int m = 0; m < 2; ++m)
#pragma unroll
    for (int ks = 0; ks < 2; ++ks) {
      int r = w * 32 + m * 16 + lr;
      qa[m][ks] = *reinterpret_cast<const s16x8*>(
          Ps + ((r * 128 + ks * 64 + lg * 16) ^ ((r & 7) << 4)));
    }
  // (next __syncthreads separates these reads from iter-0 P writes)

  f32x4 octx[2][4] = {};
  float mrun[2][4], lrun[2][4];
#pragma unroll
  for (int m = 0; m < 2; ++m)
#pragma unroll
    for (int r = 0; r < 4; ++r) { mrun[m][r] = -1e30f; lrun[m][r] = 0.0f; }

  for (int it = 0; it < 16; ++it) {
    int kv0 = it * 128;
    // ---- stage K [128][64] swz, V^T [64][128] swz
    {
      int row = t >> 3, cb = (t & 7) * 16;
#pragma unroll
      for (int i = 0; i < 4; ++i) {
        int r = i * 32 + row;
        int4 v = *reinterpret_cast<const int4*>(kp + (size_t)(kv0 + r) * 1024 + (t & 7) * 8);
        *reinterpret_cast<int4*>(Ks + ((r * 128 + cb) ^ ((r & 7) << 4))) = v;
      }
      int vrow = t >> 4, vcb = (t & 15) * 16;
#pragma unroll
      for (int i = 0; i < 4; ++i) {
        int r = i * 16 + vrow;
        int4 v = *reinterpret_cast<const int4*>(vp + (size_t)r * 2048 + kv0 + (t & 15) * 8);
        *reinterpret_cast<int4*>(Vs + ((r * 256 + vcb) ^ ((r & 7) << 4))) = v;
      }
    }
    __syncthreads();

    // ---- S = Q K^T : per wave 32q x 128k
    f32x4 s[2][8] = {};
#pragma unroll
    for (int ks = 0; ks < 2; ++ks) {
      s16x8 kb[8];
#pragma unroll
      for (int n = 0; n < 8; ++n) {
        int r = n * 16 + lr;
        kb[n] = *reinterpret_cast<const s16x8*>(
            Ks + ((r * 128 + ks * 64 + lg * 16) ^ ((r & 7) << 4)));
      }
#pragma unroll
      for (int m = 0; m < 2; ++m)
#pragma unroll
        for (int n = 0; n < 8; ++n)
          s[m][n] = __builtin_amdgcn_mfma_f32_16x16x32_bf16(qa[m][ks], kb[n], s[m][n], 0, 0, 0);
    }

    // ---- online softmax (rows are wave-local; 16 lanes/row share stats)
#pragma unroll
    for (int m = 0; m < 2; ++m)
#pragma unroll
      for (int r = 0; r < 4; ++r) {
        float mx = s[m][0][r];
#pragma unroll
        for (int n = 1; n < 8; ++n) mx = fmaxf(mx, s[m][n][r]);
        mx = fmaxf(mx, __shfl_xor(mx, 1));
        mx = fmaxf(mx, __shfl_xor(mx, 2));
        mx = fmaxf(mx, __shfl_xor(mx, 4));
        mx = fmaxf(mx, __shfl_xor(mx, 8));
        float mnew = fmaxf(mrun[m][r], mx);
        float scale = __expf(mrun[m][r] - mnew);
        float rs = 0.0f;
#pragma unroll
        for (int n = 0; n < 8; ++n) {
          float p = __expf(s[m][n][r] - mnew);
          s[m][n][r] = p;
          rs += p;
        }
        rs += __shfl_xor(rs, 1);
        rs += __shfl_xor(rs, 2);
        rs += __shfl_xor(rs, 4);
        rs += __shfl_xor(rs, 8);
        lrun[m][r] = lrun[m][r] * scale + rs;
        mrun[m][r] = mnew;
#pragma unroll
        for (int nd = 0; nd < 4; ++nd) octx[m][nd][r] *= scale;
      }

    // ---- write P (bf16, swizzled) to wave-private LDS
#pragma unroll
    for (int m = 0; m < 2; ++m)
#pragma unroll
      for (int r = 0; r < 4; ++r) {
        int row = m * 16 + lg * 4 + r;
#pragma unroll
        for (int n = 0; n < 8; ++n) {
          int byte = w * 8192 + (((row * 256) + (n * 16 + lr) * 2) ^ ((row & 7) << 4));
          *reinterpret_cast<unsigned short*>(Ps + byte) = f2bf(s[m][n][r]);
        }
      }
    __syncthreads();  // safety: order P writes before PV reads

    // ---- ctx += P V
#pragma unroll
    for (int ks = 0; ks < 4; ++ks) {
      s16x8 pa[2], vb[4];
#pragma unroll
      for (int m = 0; m < 2; ++m) {
        int row = m * 16 + lr;
        pa[m] = *reinterpret_cast<const s16x8*>(
            Ps + w * 8192 + ((row * 256 + ks * 64 + lg * 16) ^ ((row & 7) << 4)));
      }
#pragma unroll
      for (int nd = 0; nd < 4; ++nd) {
        int row = nd * 16 + lr;
        vb[nd] = *reinterpret_cast<const s16x8*>(
            Vs + ((row * 256 + ks * 64 + lg * 16) ^ ((row & 7) << 4)));
      }
#pragma unroll
      for (int m = 0; m < 2; ++m)
#pragma unroll
        for (int nd = 0; nd < 4; ++nd)
          octx[m][nd] = __builtin_amdgcn_mfma_f32_16x16x32_bf16(pa[m], vb[nd], octx[m][nd], 0, 0, 0);
    }
    __syncthreads();  // before restaging Ks/Vs
  }

  // ---- epilogue: ctx / l -> bf16
#pragma unroll
  for (int m = 0; m < 2; ++m)
#pragma unroll
    for (int r = 0; r < 4; ++r) {
      float inv = 1.0f / lrun[m][r];
      int qrow = qt * 128 + w * 32 + m * 16 + lg * 4 + r;
#pragma unroll
      for (int nd = 0; nd < 4; ++nd)
        ctx[(size_t)(b * 2048 + qrow) * 1024 + h * 64 + nd * 16 + lr] =
            f2bf(octx[m][nd][r] * inv);
    }
}

// ---------------------------------------------------------------------------
// Launch
// ---------------------------------------------------------------------------
extern "C" void kernel_launch(void* const* d_in, const int* in_sizes, int n_in,
                              void* d_out, int out_size, void* d_ws, size_t ws_size,
                              hipStream_t stream) {
  const float* hs  = (const float*)d_in[0];
  const float* kvs = (const float*)d_in[1];
  const float* wq  = (const float*)d_in[2];
  const float* wk  = (const float*)d_in[3];
  const float* wv  = (const float*)d_in[4];
  const float* wo  = (const float*)d_in[5];
  const float* nw  = (const float*)d_in[6];
  float* out = (float*)d_out;
  char* ws = (char*)d_ws;

  unsigned short* normed = (unsigned short*)(ws + (size_t)0);
  unsigned short* kvb    = (unsigned short*)(ws + ((size_t)8 << 20));
  unsigned short* wqT    = (unsigned short*)(ws + ((size_t)16 << 20));
  unsigned short* wkT    = (unsigned short*)(ws + ((size_t)18 << 20));
  unsigned short* wvT    = (unsigned short*)(ws + ((size_t)20 << 20));
  unsigned short* woT    = (unsigned short*)(ws + ((size_t)22 << 20));
  unsigned short* qb     = (unsigned short*)(ws + ((size_t)24 << 20));
  unsigned short* kb     = (unsigned short*)(ws + ((size_t)32 << 20));
  unsigned short* vTb    = (unsigned short*)(ws + ((size_t)40 << 20));
  unsigned short* ctxb   = (unsigned short*)(ws + ((size_t)48 << 20));

  dim3 tg(16, 16);
  k_transpose_cast<<<tg, 256, 0, stream>>>(wq, wqT);
  k_transpose_cast<<<tg, 256, 0, stream>>>(wk, wkT);
  k_transpose_cast<<<tg, 256, 0, stream>>>(wv, wvT);
  k_transpose_cast<<<tg, 256, 0, stream>>>(wo, woT);
  k_rmsnorm<<<4096, 256, 0, stream>>>(hs, nw, normed);
  k_cast<<<1024, 256, 0, stream>>>(kvs, kvb, 1048576);

  dim3 gg(8, 32);
  k_gemm<0><<<gg, 256, 0, stream>>>(normed, wqT, (void*)qb, nullptr);
  k_gemm<0><<<gg, 256, 0, stream>>>(kvb, wkT, (void*)kb, nullptr);
  k_gemm<1><<<gg, 256, 0, stream>>>(kvb, wvT, (void*)vTb, nullptr);

  dim3 ag(16, 32);
  k_attn<<<ag, 256, 0, stream>>>(qb, kb, vTb, ctxb);

  k_gemm<2><<<gg, 256, 0, stream>>>(ctxb, woT, (void*)out, hs);
}

// Round 5
// 177.761 us; speedup vs baseline: 1.4232x; 1.4232x over previous
//
#include <hip/hip_runtime.h>

// ---------------------------------------------------------------------------
// T5 cross-attention fused pipeline for MI355X (gfx950)  — round 5
// B=2, Q=KV=2048, D_MODEL=1024, H=16, D=64
// Round-4 tr_read P-path produced garbage (unverified HW lane mapping);
// reverted P-bounce to round-1's proven scalar-write + swizzled b128 read.
// ---------------------------------------------------------------------------

typedef __attribute__((ext_vector_type(8))) short  s16x8;   // 8 bf16 (A/B frag)
typedef __attribute__((ext_vector_type(4))) float  f32x4;   // C/D frag

#define LOG2E 1.4426950408889634f
#define EXP2(x) __builtin_amdgcn_exp2f(x)

__device__ __forceinline__ unsigned short f2bf(float f) {
  unsigned int u = __builtin_bit_cast(unsigned int, f);
  return (unsigned short)((u + 0x7FFFu + ((u >> 16) & 1u)) >> 16);  // RNE
}

__device__ __forceinline__ unsigned fbits(float f) {
  return __builtin_bit_cast(unsigned, f);
}

__device__ __forceinline__ void gload16(const void* g, void* l) {
  __builtin_amdgcn_global_load_lds(
      (const __attribute__((address_space(1))) unsigned int*)g,
      (__attribute__((address_space(3))) unsigned int*)l, 16, 0, 0);
}

// ---------------------------------------------------------------------------
// Transpose-cast x4 in one dispatch: out[n][k] = bf16(in[k][n]), 1024x1024
// ---------------------------------------------------------------------------
__global__ __launch_bounds__(256) void k_transpose4(
    const float* __restrict__ a0, const float* __restrict__ a1,
    const float* __restrict__ a2, const float* __restrict__ a3,
    unsigned short* __restrict__ o0, unsigned short* __restrict__ o1,
    unsigned short* __restrict__ o2, unsigned short* __restrict__ o3) {
  int z = blockIdx.z;
  const float* in = (z == 0) ? a0 : (z == 1) ? a1 : (z == 2) ? a2 : a3;
  unsigned short* out = (z == 0) ? o0 : (z == 1) ? o1 : (z == 2) ? o2 : o3;
  __shared__ float tile[64][65];
  int t = threadIdx.x;
  int tx = t & 15, ty = t >> 4;
  int r0 = blockIdx.y * 64, c0 = blockIdx.x * 64;
#pragma unroll
  for (int p = 0; p < 4; ++p) {
    int r = p * 16 + ty;
    float4 v = *reinterpret_cast<const float4*>(in + (size_t)(r0 + r) * 1024 + c0 + tx * 4);
    tile[r][tx * 4 + 0] = v.x; tile[r][tx * 4 + 1] = v.y;
    tile[r][tx * 4 + 2] = v.z; tile[r][tx * 4 + 3] = v.w;
  }
  __syncthreads();
#pragma unroll
  for (int p = 0; p < 4; ++p) {
    int c = p * 16 + ty;
    unsigned int lo = (unsigned int)f2bf(tile[tx * 4 + 0][c]) |
                      ((unsigned int)f2bf(tile[tx * 4 + 1][c]) << 16);
    unsigned int hi = (unsigned int)f2bf(tile[tx * 4 + 2][c]) |
                      ((unsigned int)f2bf(tile[tx * 4 + 3][c]) << 16);
    uint2 pk; pk.x = lo; pk.y = hi;
    *reinterpret_cast<uint2*>(out + (size_t)(c0 + c) * 1024 + r0 + tx * 4) = pk;
  }
}

// ---------------------------------------------------------------------------
// RMSNorm + cast to bf16, scaled by log2(e) (feeds ONLY the Q projection ->
// QK^T scores land in the exp2 domain for free).
// ---------------------------------------------------------------------------
__global__ __launch_bounds__(256) void k_rmsnorm(
    const float* __restrict__ hs, const float* __restrict__ w,
    unsigned short* __restrict__ out) {
  int row = blockIdx.x, t = threadIdx.x;
  float4 v = *reinterpret_cast<const float4*>(hs + (size_t)row * 1024 + t * 4);
  float s = v.x * v.x + v.y * v.y + v.z * v.z + v.w * v.w;
#pragma unroll
  for (int m = 1; m < 64; m <<= 1) s += __shfl_xor(s, m);
  __shared__ float ps[4];
  if ((t & 63) == 0) ps[t >> 6] = s;
  __syncthreads();
  float tot = ps[0] + ps[1] + ps[2] + ps[3];
  float sc = rsqrtf(tot * (1.0f / 1024.0f) + 1e-6f) * LOG2E;
  float4 wv = *reinterpret_cast<const float4*>(w + t * 4);
  unsigned int lo = (unsigned int)f2bf(v.x * sc * wv.x) |
                    ((unsigned int)f2bf(v.y * sc * wv.y) << 16);
  unsigned int hi = (unsigned int)f2bf(v.z * sc * wv.z) |
                    ((unsigned int)f2bf(v.w * sc * wv.w) << 16);
  uint2 pk; pk.x = lo; pk.y = hi;
  *reinterpret_cast<uint2*>(out + (size_t)row * 1024 + t * 4) = pk;
}

// ---------------------------------------------------------------------------
// Plain f32 -> bf16 cast
// ---------------------------------------------------------------------------
__global__ __launch_bounds__(256) void k_cast(
    const float* __restrict__ in, unsigned short* __restrict__ out, int n4) {
  int i = blockIdx.x * 256 + threadIdx.x;
  int stride = gridDim.x * 256;
  for (; i < n4; i += stride) {
    float4 v = *reinterpret_cast<const float4*>(in + (size_t)i * 4);
    unsigned int lo = (unsigned int)f2bf(v.x) | ((unsigned int)f2bf(v.y) << 16);
    unsigned int hi = (unsigned int)f2bf(v.z) | ((unsigned int)f2bf(v.w) << 16);
    uint2 pk; pk.x = lo; pk.y = hi;
    *reinterpret_cast<uint2*>(out + (size_t)i * 4) = pk;
  }
}

// ---------------------------------------------------------------------------
// GEMM body: C[M,N] = A[M,K] * Bt[N,K]^T (M=4096, N=1024, K=1024, bf16 in)
// 128x128 tile, BK=64, double-buffered LDS, 2-phase prefetch.
// mode 0: bf16 out; mode 1: bf16 out transposed to vT [b][h][d][2048];
// mode 2: f32 out + residual
// ---------------------------------------------------------------------------
__device__ __forceinline__ void gemm_body(
    const unsigned short* __restrict__ A, const unsigned short* __restrict__ Bt,
    void* __restrict__ Cout, const float* __restrict__ resid, int mode) {
  __shared__ __align__(16) char sm[65536];
  // As0 @0, As1 @16K, Bs0 @32K, Bs1 @48K
  int t = threadIdx.x;
  int bn = blockIdx.x, bm = blockIdx.y;
  int m0 = bm * 128, n0 = bn * 128;
  int lane = t & 63, w = t >> 6, lr = lane & 15, lg = lane >> 4;
  int wr = w >> 1, wc = w & 1;

  f32x4 acc[4][4] = {};

  const char* aA = (const char*)A + ((size_t)(m0 + (t >> 3)) * 1024 + (t & 7) * 8) * 2;
  const char* aB = (const char*)Bt + ((size_t)(n0 + (t >> 3)) * 1024 + (t & 7) * 8) * 2;

  auto stage = [&](int buf, int kt) {
    int koff = kt * 128;  // bytes into the K dimension
    char* As = sm + buf * 16384;
    char* Bs = sm + 32768 + buf * 16384;
#pragma unroll
    for (int c = 0; c < 4; ++c) {
      gload16(aA + (size_t)c * 65536 + koff, As + c * 4096 + t * 16);
      gload16(aB + (size_t)c * 65536 + koff, Bs + c * 4096 + t * 16);
    }
  };

  stage(0, 0);
  __syncthreads();
  int cur = 0;
  for (int kt = 0; kt < 16; ++kt) {
    if (kt < 15) stage(cur ^ 1, kt + 1);
    const char* As = sm + cur * 16384;
    const char* Bs = sm + 32768 + cur * 16384;
    s16x8 af[2][4], bfr[2][4];
#pragma unroll
    for (int ks = 0; ks < 2; ++ks) {
#pragma unroll
      for (int m = 0; m < 4; ++m)
        af[ks][m] = *reinterpret_cast<const s16x8*>(
            As + (wr * 64 + m * 16 + lr) * 128 + ks * 64 + lg * 16);
#pragma unroll
      for (int n = 0; n < 4; ++n)
        bfr[ks][n] = *reinterpret_cast<const s16x8*>(
            Bs + (wc * 64 + n * 16 + lr) * 128 + ks * 64 + lg * 16);
    }
#pragma unroll
    for (int ks = 0; ks < 2; ++ks)
#pragma unroll
      for (int m = 0; m < 4; ++m)
#pragma unroll
        for (int n = 0; n < 4; ++n)
          acc[m][n] = __builtin_amdgcn_mfma_f32_16x16x32_bf16(af[ks][m], bfr[ks][n], acc[m][n], 0, 0, 0);
    __syncthreads();
    cur ^= 1;
  }

#pragma unroll
  for (int m = 0; m < 4; ++m)
#pragma unroll
    for (int n = 0; n < 4; ++n) {
      int colg = n0 + wc * 64 + n * 16 + lr;
      int rowb = m0 + wr * 64 + m * 16 + lg * 4;
      if (mode == 0) {
        unsigned short* C = (unsigned short*)Cout;
#pragma unroll
        for (int r = 0; r < 4; ++r)
          C[(size_t)(rowb + r) * 1024 + colg] = f2bf(acc[m][n][r]);
      } else if (mode == 1) {
        int h = colg >> 6, d = colg & 63;
        int b = rowb >> 11, kv = rowb & 2047;
        unsigned short* C = (unsigned short*)Cout +
            ((size_t)((b * 16 + h) * 64 + d) * 2048 + kv);
        unsigned int lo = (unsigned int)f2bf(acc[m][n][0]) |
                          ((unsigned int)f2bf(acc[m][n][1]) << 16);
        unsigned int hi = (unsigned int)f2bf(acc[m][n][2]) |
                          ((unsigned int)f2bf(acc[m][n][3]) << 16);
        uint2 pk; pk.x = lo; pk.y = hi;
        *reinterpret_cast<uint2*>(C) = pk;
      } else {
        float* C = (float*)Cout;
#pragma unroll
        for (int r = 0; r < 4; ++r) {
          size_t idx = (size_t)(rowb + r) * 1024 + colg;
          C[idx] = resid[idx] + acc[m][n][r];
        }
      }
    }
}

__global__ __launch_bounds__(256) void k_gemm_qkv(
    const unsigned short* __restrict__ normed, const unsigned short* __restrict__ kvb,
    const unsigned short* __restrict__ wqT, const unsigned short* __restrict__ wkT,
    const unsigned short* __restrict__ wvT,
    unsigned short* __restrict__ qb, unsigned short* __restrict__ kb,
    unsigned short* __restrict__ vTb) {
  int z = blockIdx.z;
  const unsigned short* A = (z == 0) ? normed : kvb;
  const unsigned short* B = (z == 0) ? wqT : (z == 1) ? wkT : wvT;
  void* C = (z == 0) ? (void*)qb : (z == 1) ? (void*)kb : (void*)vTb;
  gemm_body(A, B, C, nullptr, (z == 2) ? 1 : 0);
}

__global__ __launch_bounds__(256) void k_gemm_o(
    const unsigned short* __restrict__ ctxb, const unsigned short* __restrict__ woT,
    float* __restrict__ out, const float* __restrict__ hs) {
  gemm_body(ctxb, woT, (void*)out, hs, 2);
}

// ---------------------------------------------------------------------------
// Flash attention, round 5.
// Grid (16 q-tiles, 32 b*h), block 256 = 4 waves; wave owns 32 q-rows.
// Scores arrive pre-scaled by log2e (RMSNorm fold) -> exp2 softmax.
// LDS (48KB): Ks[128][64] swz (16K) | Vs[64][128] swz (16K) |
//             P per-wave [16 q][128 kv] swz (4K x 4 waves = 16K).
// Staging: global_load_lds with pre-unswizzled per-lane source addresses.
// P path: round-1-proven scalar b16 writes (RTZ) + swizzled ds_read_b128,
// processed per 16-row half (mm) to halve the P footprint.
// ---------------------------------------------------------------------------
__global__ __launch_bounds__(256) void k_attn(
    const unsigned short* __restrict__ q, const unsigned short* __restrict__ k,
    const unsigned short* __restrict__ vt, unsigned short* __restrict__ ctx) {
  __shared__ __align__(16) char sm[49152];
  char* Ks = sm;            // 16384
  char* Vs = sm + 16384;    // 16384
  char* Ps = sm + 32768;    // 16384 (4 x 4096)
  int t = threadIdx.x, w = t >> 6, lane = t & 63, lr = lane & 15, lg = lane >> 4;
  int qt = blockIdx.x, bh = blockIdx.y, b = bh >> 4, h = bh & 15;

  const char* qB = (const char*)q + ((size_t)(b * 2048 + qt * 128) * 1024 + h * 64) * 2;
  const char* kB = (const char*)k + ((size_t)(b * 2048) * 1024 + h * 64) * 2;
  const char* vB = (const char*)vt + (size_t)bh * 64 * 4096;

  // staging geometry (pre-unswizzled sources; dest is lane-linear)
  // K/Q rows: r = c*32 + (t>>3), col byte = ((t&7)*16) ^ ((r&7)<<4)
  int krow = t >> 3;
  int kcb  = ((t & 7) * 16) ^ ((krow & 7) << 4);
  // V rows: d = c*16 + (t>>4), col byte = ((t&15)*16) ^ ((d&7)<<4)
  int vrow = t >> 4;
  int vcb  = ((t & 15) * 16) ^ ((vrow & 7) << 4);

  // ---- stage Q into Ks area (one-time), read frags, then barrier
#pragma unroll
  for (int c = 0; c < 4; ++c)
    gload16(qB + (size_t)(c * 32 + krow) * 2048 + kcb, Ks + c * 4096 + t * 16);
  __syncthreads();
  s16x8 qa[2][2];
#pragma unroll
  for (int m = 0; m < 2; ++m)
#pragma unroll
    for (int ks = 0; ks < 2; ++ks) {
      int row = w * 32 + m * 16 + lr;
      qa[m][ks] = *reinterpret_cast<const s16x8*>(
          Ks + row * 128 + (((ks * 64 + lg * 16)) ^ ((lr & 7) << 4)));
    }
  __syncthreads();  // all q-frag reads done before K staging overwrites Ks

  // per-lane staging source pointers
  const char* kSrc[4];
  const char* vSrc[4];
#pragma unroll
  for (int c = 0; c < 4; ++c) {
    kSrc[c] = kB + (size_t)(c * 32 + krow) * 2048 + kcb;
    vSrc[c] = vB + (size_t)(c * 16 + vrow) * 4096 + vcb;
  }

  char* Pw = Ps + w * 4096;  // per-wave [16 q][128 kv] bf16, 256B pitch, swz

  f32x4 octx[2][4] = {};
  float mrun[2][4], lsum[2][4];
#pragma unroll
  for (int m = 0; m < 2; ++m)
#pragma unroll
    for (int r = 0; r < 4; ++r) { mrun[m][r] = -1e30f; lsum[m][r] = 0.0f; }

  for (int it = 0; it < 16; ++it) {
    // ---- stage K [128][64] + V^T [64][128] (swizzled images, direct to LDS)
#pragma unroll
    for (int c = 0; c < 4; ++c) {
      gload16(kSrc[c], Ks + c * 4096 + t * 16);
      gload16(vSrc[c], Vs + c * 4096 + t * 16);
      kSrc[c] += 128 * 2048;
      vSrc[c] += 256;
    }
    __syncthreads();

    // ---- S = Q K^T  (scores already in log2 domain)
    f32x4 s_[2][8] = {};
#pragma unroll
    for (int ks = 0; ks < 2; ++ks) {
      s16x8 kbr[8];
#pragma unroll
      for (int n = 0; n < 8; ++n)
        kbr[n] = *reinterpret_cast<const s16x8*>(
            Ks + (n * 16 + lr) * 128 + ((ks * 64 + lg * 16) ^ ((lr & 7) << 4)));
#pragma unroll
      for (int m = 0; m < 2; ++m)
#pragma unroll
        for (int n = 0; n < 8; ++n)
          s_[m][n] = __builtin_amdgcn_mfma_f32_16x16x32_bf16(qa[m][ks], kbr[n], s_[m][n], 0, 0, 0);
    }

    // ---- online softmax: defer-max (THR=8 in log2 units), lazy sum reduce
    float lmx[2][4];
#pragma unroll
    for (int m = 0; m < 2; ++m)
#pragma unroll
      for (int r = 0; r < 4; ++r) {
        float v = s_[m][0][r];
#pragma unroll
        for (int n = 1; n < 8; ++n) v = fmaxf(v, s_[m][n][r]);
        lmx[m][r] = v;
      }
    int need = 0;
#pragma unroll
    for (int m = 0; m < 2; ++m)
#pragma unroll
      for (int r = 0; r < 4; ++r)
        need |= (lmx[m][r] > mrun[m][r] + 8.0f) ? 1 : 0;
    if (__any(need)) {
#pragma unroll
      for (int m = 0; m < 2; ++m)
#pragma unroll
        for (int r = 0; r < 4; ++r) {
          float mx = fmaxf(lmx[m][r], mrun[m][r]);
          mx = fmaxf(mx, __shfl_xor(mx, 1));
          mx = fmaxf(mx, __shfl_xor(mx, 2));
          mx = fmaxf(mx, __shfl_xor(mx, 4));
          mx = fmaxf(mx, __shfl_xor(mx, 8));
          float sc = EXP2(mrun[m][r] - mx);
          mrun[m][r] = mx;
          lsum[m][r] *= sc;
#pragma unroll
          for (int nd = 0; nd < 4; ++nd) octx[m][nd][r] *= sc;
        }
    }

    // ---- per-m-half: exp2 + scalar P writes (RTZ, swizzled), then PV
#pragma unroll
    for (int mm = 0; mm < 2; ++mm) {
#pragma unroll
      for (int r = 0; r < 4; ++r) {
        int qrow = lg * 4 + r;              // [0,16)
        int rowbase = qrow * 256;
        int mask = (qrow & 7) << 4;
#pragma unroll
        for (int n = 0; n < 8; ++n) {
          float p = EXP2(s_[mm][n][r] - mrun[mm][r]);
          lsum[mm][r] += p;
          *reinterpret_cast<unsigned short*>(
              Pw + rowbase + (((n * 16 + lr) * 2) ^ mask)) =
              (unsigned short)(fbits(p) >> 16);  // RTZ bf16
        }
      }
      // same-wave LDS ordering (in-order DS pipe) makes writes visible to
      // the reads below without a barrier; P buffer is wave-private.
#pragma unroll
      for (int ks = 0; ks < 4; ++ks) {
        s16x8 pa = *reinterpret_cast<const s16x8*>(
            Pw + lr * 256 + ((ks * 64 + lg * 16) ^ ((lr & 7) << 4)));
        s16x8 vbr[4];
#pragma unroll
        for (int nd = 0; nd < 4; ++nd)
          vbr[nd] = *reinterpret_cast<const s16x8*>(
              Vs + (nd * 16 + lr) * 256 + ((ks * 64 + lg * 16) ^ ((lr & 7) << 4)));
#pragma unroll
        for (int nd = 0; nd < 4; ++nd)
          octx[mm][nd] = __builtin_amdgcn_mfma_f32_16x16x32_bf16(pa, vbr[nd], octx[mm][nd], 0, 0, 0);
      }
    }
    __syncthreads();  // before restaging Ks/Vs
  }

  // ---- epilogue: cross-lane sum reduce, normalize, store bf16
#pragma unroll
  for (int m = 0; m < 2; ++m)
#pragma unroll
    for (int r = 0; r < 4; ++r) {
      float tot = lsum[m][r];
      tot += __shfl_xor(tot, 1);
      tot += __shfl_xor(tot, 2);
      tot += __shfl_xor(tot, 4);
      tot += __shfl_xor(tot, 8);
      float inv = 1.0f / tot;
      int qrow = qt * 128 + w * 32 + m * 16 + lg * 4 + r;
#pragma unroll
      for (int nd = 0; nd < 4; ++nd)
        ctx[(size_t)(b * 2048 + qrow) * 1024 + h * 64 + nd * 16 + lr] =
            f2bf(octx[m][nd][r] * inv);
    }
}

// ---------------------------------------------------------------------------
// Launch
// ---------------------------------------------------------------------------
extern "C" void kernel_launch(void* const* d_in, const int* in_sizes, int n_in,
                              void* d_out, int out_size, void* d_ws, size_t ws_size,
                              hipStream_t stream) {
  const float* hs  = (const float*)d_in[0];
  const float* kvs = (const float*)d_in[1];
  const float* wq  = (const float*)d_in[2];
  const float* wk  = (const float*)d_in[3];
  const float* wv  = (const float*)d_in[4];
  const float* wo  = (const float*)d_in[5];
  const float* nw  = (const float*)d_in[6];
  float* out = (float*)d_out;
  char* ws = (char*)d_ws;

  unsigned short* normed = (unsigned short*)(ws + (size_t)0);
  unsigned short* kvb    = (unsigned short*)(ws + ((size_t)8 << 20));
  unsigned short* wqT    = (unsigned short*)(ws + ((size_t)16 << 20));
  unsigned short* wkT    = (unsigned short*)(ws + ((size_t)18 << 20));
  unsigned short* wvT    = (unsigned short*)(ws + ((size_t)20 << 20));
  unsigned short* woT    = (unsigned short*)(ws + ((size_t)22 << 20));
  unsigned short* qb     = (unsigned short*)(ws + ((size_t)24 << 20));
  unsigned short* kb     = (unsigned short*)(ws + ((size_t)32 << 20));
  unsigned short* vTb    = (unsigned short*)(ws + ((size_t)40 << 20));
  unsigned short* ctxb   = (unsigned short*)(ws + ((size_t)48 << 20));

  k_transpose4<<<dim3(16, 16, 4), 256, 0, stream>>>(wq, wk, wv, wo, wqT, wkT, wvT, woT);
  k_rmsnorm<<<4096, 256, 0, stream>>>(hs, nw, normed);
  k_cast<<<1024, 256, 0, stream>>>(kvs, kvb, 1048576);

  k_gemm_qkv<<<dim3(8, 32, 3), 256, 0, stream>>>(normed, kvb, wqT, wkT, wvT, qb, kb, vTb);

  k_attn<<<dim3(16, 32), 256, 0, stream>>>(qb, kb, vTb, ctxb);

  k_gemm_o<<<dim3(8, 32), 256, 0, stream>>>(ctxb, woT, out, hs);
}

// Round 7
// 168.320 us; speedup vs baseline: 1.5030x; 1.0561x over previous
//
#include <hip/hip_runtime.h>

// ---------------------------------------------------------------------------
// T5 cross-attention fused pipeline for MI355X (gfx950)  — round 7 (= round 6
// resubmitted; round 6 bench died with an infra error before running)
// B=2, Q=KV=2048, D_MODEL=1024, H=16, D=64
// attn: K/V double-buffer + raw-barrier pipeline, V-frag hoist, conflict-free
// P-write swizzle, XCD-aware head clustering.
// ---------------------------------------------------------------------------

typedef __attribute__((ext_vector_type(8))) short  s16x8;   // 8 bf16 (A/B frag)
typedef __attribute__((ext_vector_type(4))) float  f32x4;   // C/D frag

#define LOG2E 1.4426950408889634f
#define EXP2(x) __builtin_amdgcn_exp2f(x)

__device__ __forceinline__ unsigned short f2bf(float f) {
  unsigned int u = __builtin_bit_cast(unsigned int, f);
  return (unsigned short)((u + 0x7FFFu + ((u >> 16) & 1u)) >> 16);  // RNE
}

__device__ __forceinline__ unsigned fbits(float f) {
  return __builtin_bit_cast(unsigned, f);
}

__device__ __forceinline__ void gload16(const void* g, void* l) {
  __builtin_amdgcn_global_load_lds(
      (const __attribute__((address_space(1))) unsigned int*)g,
      (__attribute__((address_space(3))) unsigned int*)l, 16, 0, 0);
}

// ---------------------------------------------------------------------------
// Transpose-cast x4 in one dispatch: out[n][k] = bf16(in[k][n]), 1024x1024
// ---------------------------------------------------------------------------
__global__ __launch_bounds__(256) void k_transpose4(
    const float* __restrict__ a0, const float* __restrict__ a1,
    const float* __restrict__ a2, const float* __restrict__ a3,
    unsigned short* __restrict__ o0, unsigned short* __restrict__ o1,
    unsigned short* __restrict__ o2, unsigned short* __restrict__ o3) {
  int z = blockIdx.z;
  const float* in = (z == 0) ? a0 : (z == 1) ? a1 : (z == 2) ? a2 : a3;
  unsigned short* out = (z == 0) ? o0 : (z == 1) ? o1 : (z == 2) ? o2 : o3;
  __shared__ float tile[64][65];
  int t = threadIdx.x;
  int tx = t & 15, ty = t >> 4;
  int r0 = blockIdx.y * 64, c0 = blockIdx.x * 64;
#pragma unroll
  for (int p = 0; p < 4; ++p) {
    int r = p * 16 + ty;
    float4 v = *reinterpret_cast<const float4*>(in + (size_t)(r0 + r) * 1024 + c0 + tx * 4);
    tile[r][tx * 4 + 0] = v.x; tile[r][tx * 4 + 1] = v.y;
    tile[r][tx * 4 + 2] = v.z; tile[r][tx * 4 + 3] = v.w;
  }
  __syncthreads();
#pragma unroll
  for (int p = 0; p < 4; ++p) {
    int c = p * 16 + ty;
    unsigned int lo = (unsigned int)f2bf(tile[tx * 4 + 0][c]) |
                      ((unsigned int)f2bf(tile[tx * 4 + 1][c]) << 16);
    unsigned int hi = (unsigned int)f2bf(tile[tx * 4 + 2][c]) |
                      ((unsigned int)f2bf(tile[tx * 4 + 3][c]) << 16);
    uint2 pk; pk.x = lo; pk.y = hi;
    *reinterpret_cast<uint2*>(out + (size_t)(c0 + c) * 1024 + r0 + tx * 4) = pk;
  }
}

// ---------------------------------------------------------------------------
// RMSNorm + cast to bf16, scaled by log2(e) (feeds ONLY the Q projection ->
// QK^T scores land in the exp2 domain for free).
// ---------------------------------------------------------------------------
__global__ __launch_bounds__(256) void k_rmsnorm(
    const float* __restrict__ hs, const float* __restrict__ w,
    unsigned short* __restrict__ out) {
  int row = blockIdx.x, t = threadIdx.x;
  float4 v = *reinterpret_cast<const float4*>(hs + (size_t)row * 1024 + t * 4);
  float s = v.x * v.x + v.y * v.y + v.z * v.z + v.w * v.w;
#pragma unroll
  for (int m = 1; m < 64; m <<= 1) s += __shfl_xor(s, m);
  __shared__ float ps[4];
  if ((t & 63) == 0) ps[t >> 6] = s;
  __syncthreads();
  float tot = ps[0] + ps[1] + ps[2] + ps[3];
  float sc = rsqrtf(tot * (1.0f / 1024.0f) + 1e-6f) * LOG2E;
  float4 wv = *reinterpret_cast<const float4*>(w + t * 4);
  unsigned int lo = (unsigned int)f2bf(v.x * sc * wv.x) |
                    ((unsigned int)f2bf(v.y * sc * wv.y) << 16);
  unsigned int hi = (unsigned int)f2bf(v.z * sc * wv.z) |
                    ((unsigned int)f2bf(v.w * sc * wv.w) << 16);
  uint2 pk; pk.x = lo; pk.y = hi;
  *reinterpret_cast<uint2*>(out + (size_t)row * 1024 + t * 4) = pk;
}

// ---------------------------------------------------------------------------
// Plain f32 -> bf16 cast
// ---------------------------------------------------------------------------
__global__ __launch_bounds__(256) void k_cast(
    const float* __restrict__ in, unsigned short* __restrict__ out, int n4) {
  int i = blockIdx.x * 256 + threadIdx.x;
  int stride = gridDim.x * 256;
  for (; i < n4; i += stride) {
    float4 v = *reinterpret_cast<const float4*>(in + (size_t)i * 4);
    unsigned int lo = (unsigned int)f2bf(v.x) | ((unsigned int)f2bf(v.y) << 16);
    unsigned int hi = (unsigned int)f2bf(v.z) | ((unsigned int)f2bf(v.w) << 16);
    uint2 pk; pk.x = lo; pk.y = hi;
    *reinterpret_cast<uint2*>(out + (size_t)i * 4) = pk;
  }
}

// ---------------------------------------------------------------------------
// GEMM body: C[M,N] = A[M,K] * Bt[N,K]^T (M=4096, N=1024, K=1024, bf16 in)
// 128x128 tile, BK=64, double-buffered LDS, 2-phase prefetch.
// mode 0: bf16 out; mode 1: bf16 out transposed to vT [b][h][d][2048];
// mode 2: f32 out + residual
// ---------------------------------------------------------------------------
__device__ __forceinline__ void gemm_body(
    const unsigned short* __restrict__ A, const unsigned short* __restrict__ Bt,
    void* __restrict__ Cout, const float* __restrict__ resid, int mode) {
  __shared__ __align__(16) char sm[65536];
  int t = threadIdx.x;
  int bn = blockIdx.x, bm = blockIdx.y;
  int m0 = bm * 128, n0 = bn * 128;
  int lane = t & 63, w = t >> 6, lr = lane & 15, lg = lane >> 4;
  int wr = w >> 1, wc = w & 1;

  f32x4 acc[4][4] = {};

  const char* aA = (const char*)A + ((size_t)(m0 + (t >> 3)) * 1024 + (t & 7) * 8) * 2;
  const char* aB = (const char*)Bt + ((size_t)(n0 + (t >> 3)) * 1024 + (t & 7) * 8) * 2;

  auto stage = [&](int buf, int kt) {
    int koff = kt * 128;  // bytes into the K dimension
    char* As = sm + buf * 16384;
    char* Bs = sm + 32768 + buf * 16384;
#pragma unroll
    for (int c = 0; c < 4; ++c) {
      gload16(aA + (size_t)c * 65536 + koff, As + c * 4096 + t * 16);
      gload16(aB + (size_t)c * 65536 + koff, Bs + c * 4096 + t * 16);
    }
  };

  stage(0, 0);
  __syncthreads();
  int cur = 0;
  for (int kt = 0; kt < 16; ++kt) {
    if (kt < 15) stage(cur ^ 1, kt + 1);
    const char* As = sm + cur * 16384;
    const char* Bs = sm + 32768 + cur * 16384;
    s16x8 af[2][4], bfr[2][4];
#pragma unroll
    for (int ks = 0; ks < 2; ++ks) {
#pragma unroll
      for (int m = 0; m < 4; ++m)
        af[ks][m] = *reinterpret_cast<const s16x8*>(
            As + (wr * 64 + m * 16 + lr) * 128 + ks * 64 + lg * 16);
#pragma unroll
      for (int n = 0; n < 4; ++n)
        bfr[ks][n] = *reinterpret_cast<const s16x8*>(
            Bs + (wc * 64 + n * 16 + lr) * 128 + ks * 64 + lg * 16);
    }
#pragma unroll
    for (int ks = 0; ks < 2; ++ks)
#pragma unroll
      for (int m = 0; m < 4; ++m)
#pragma unroll
        for (int n = 0; n < 4; ++n)
          acc[m][n] = __builtin_amdgcn_mfma_f32_16x16x32_bf16(af[ks][m], bfr[ks][n], acc[m][n], 0, 0, 0);
    __syncthreads();
    cur ^= 1;
  }

#pragma unroll
  for (int m = 0; m < 4; ++m)
#pragma unroll
    for (int n = 0; n < 4; ++n) {
      int colg = n0 + wc * 64 + n * 16 + lr;
      int rowb = m0 + wr * 64 + m * 16 + lg * 4;
      if (mode == 0) {
        unsigned short* C = (unsigned short*)Cout;
#pragma unroll
        for (int r = 0; r < 4; ++r)
          C[(size_t)(rowb + r) * 1024 + colg] = f2bf(acc[m][n][r]);
      } else if (mode == 1) {
        int h = colg >> 6, d = colg & 63;
        int b = rowb >> 11, kv = rowb & 2047;
        unsigned short* C = (unsigned short*)Cout +
            ((size_t)((b * 16 + h) * 64 + d) * 2048 + kv);
        unsigned int lo = (unsigned int)f2bf(acc[m][n][0]) |
                          ((unsigned int)f2bf(acc[m][n][1]) << 16);
        unsigned int hi = (unsigned int)f2bf(acc[m][n][2]) |
                          ((unsigned int)f2bf(acc[m][n][3]) << 16);
        uint2 pk; pk.x = lo; pk.y = hi;
        *reinterpret_cast<uint2*>(C) = pk;
      } else {
        float* C = (float*)Cout;
#pragma unroll
        for (int r = 0; r < 4; ++r) {
          size_t idx = (size_t)(rowb + r) * 1024 + colg;
          C[idx] = resid[idx] + acc[m][n][r];
        }
      }
    }
}

__global__ __launch_bounds__(256) void k_gemm_qkv(
    const unsigned short* __restrict__ normed, const unsigned short* __restrict__ kvb,
    const unsigned short* __restrict__ wqT, const unsigned short* __restrict__ wkT,
    const unsigned short* __restrict__ wvT,
    unsigned short* __restrict__ qb, unsigned short* __restrict__ kb,
    unsigned short* __restrict__ vTb) {
  int z = blockIdx.z;
  const unsigned short* A = (z == 0) ? normed : kvb;
  const unsigned short* B = (z == 0) ? wqT : (z == 1) ? wkT : wvT;
  void* C = (z == 0) ? (void*)qb : (z == 1) ? (void*)kb : (void*)vTb;
  gemm_body(A, B, C, nullptr, (z == 2) ? 1 : 0);
}

__global__ __launch_bounds__(256) void k_gemm_o(
    const unsigned short* __restrict__ ctxb, const unsigned short* __restrict__ woT,
    float* __restrict__ out, const float* __restrict__ hs) {
  gemm_body(ctxb, woT, (void*)out, hs, 2);
}

// ---------------------------------------------------------------------------
// Flash attention.
// Grid: 512 blocks 1D (XCD-clustered: 4 heads per XCD); block 256 = 4 waves.
// LDS (80KB): Ks dbuf 2x16K | Vs dbuf 2x16K | P 4x4K.
// Pipeline: issue stage(next) at iter top; compute current; vmcnt(0) +
// raw s_barrier at iter end (loads fly under the compute).
// P path: conflict-free scalar writes (XOR key lg<<5) + swizzled b128 reads.
// ---------------------------------------------------------------------------
__global__ __launch_bounds__(256) void k_attn(
    const unsigned short* __restrict__ q, const unsigned short* __restrict__ k,
    const unsigned short* __restrict__ vt, unsigned short* __restrict__ ctx) {
  __shared__ __align__(16) char sm[81920];
  // Ks0 @0, Ks1 @16K, Vs0 @32K, Vs1 @48K, P @64K (4KB/wave)
  int t = threadIdx.x, w = t >> 6, lane = t & 63, lr = lane & 15, lg = lane >> 4;

  // XCD-aware decomposition: 64 consecutive-slot blocks per XCD = 4 heads
  int bid = blockIdx.x;
  int xcd = bid & 7, slot = bid >> 3;
  int bh = xcd * 4 + (slot >> 4);   // [0,32)
  int qt = slot & 15;               // [0,16)
  int b = bh >> 4, h = bh & 15;

  const char* qB = (const char*)q + ((size_t)(b * 2048 + qt * 128) * 1024 + h * 64) * 2;
  const char* kB = (const char*)k + ((size_t)(b * 2048) * 1024 + h * 64) * 2;
  const char* vB = (const char*)vt + (size_t)bh * 64 * 4096;

  // staging geometry (pre-unswizzled sources; dest is lane-linear)
  int krow = t >> 3;
  int kcb  = ((t & 7) * 16) ^ ((krow & 7) << 4);
  int vrow = t >> 4;
  int vcb  = ((t & 15) * 16) ^ ((vrow & 7) << 4);

  auto stageKV = [&](int buf, int it2) {
    char* Kd = sm + buf * 16384;
    char* Vd = sm + 32768 + buf * 16384;
    const char* kb2 = kB + (size_t)(it2 * 128) * 2048;
    const char* vb2 = vB + it2 * 256;
#pragma unroll
    for (int c = 0; c < 4; ++c) {
      gload16(kb2 + (size_t)(c * 32 + krow) * 2048 + kcb, Kd + c * 4096 + t * 16);
      gload16(vb2 + (size_t)(c * 16 + vrow) * 4096 + vcb, Vd + c * 4096 + t * 16);
    }
  };

  // ---- prologue: stage Q into Ks0, read frags, then prefetch tile 0
#pragma unroll
  for (int c = 0; c < 4; ++c)
    gload16(qB + (size_t)(c * 32 + krow) * 2048 + kcb, sm + c * 4096 + t * 16);
  __syncthreads();
  s16x8 qa[2][2];
#pragma unroll
  for (int m = 0; m < 2; ++m)
#pragma unroll
    for (int ks = 0; ks < 2; ++ks) {
      int row = w * 32 + m * 16 + lr;
      qa[m][ks] = *reinterpret_cast<const s16x8*>(
          sm + row * 128 + ((ks * 64 + lg * 16) ^ ((lr & 7) << 4)));
    }
  __syncthreads();  // all q-frag reads done before staging overwrites Ks0
  stageKV(0, 0);
  asm volatile("s_waitcnt vmcnt(0)" ::: "memory");
  __builtin_amdgcn_s_barrier();
  __builtin_amdgcn_sched_barrier(0);

  char* Pw = sm + 65536 + w * 4096;  // per-wave [16 q][128 kv] bf16, swz

  f32x4 octx[2][4] = {};
  float mrun[2][4], lsum[2][4];
#pragma unroll
  for (int m = 0; m < 2; ++m)
#pragma unroll
    for (int r = 0; r < 4; ++r) { mrun[m][r] = -1e30f; lsum[m][r] = 0.0f; }

  int cur = 0;
  for (int it = 0; it < 16; ++it) {
    // ---- issue next tile's staging (completes under this iter's compute)
    if (it < 15) stageKV(cur ^ 1, it + 1);

    const char* Ks = sm + cur * 16384;
    const char* Vs = sm + 32768 + cur * 16384;

    // ---- S = Q K^T  (scores already in log2 domain)
    f32x4 s_[2][8] = {};
#pragma unroll
    for (int ks = 0; ks < 2; ++ks) {
      s16x8 kbr[8];
#pragma unroll
      for (int n = 0; n < 8; ++n)
        kbr[n] = *reinterpret_cast<const s16x8*>(
            Ks + (n * 16 + lr) * 128 + ((ks * 64 + lg * 16) ^ ((lr & 7) << 4)));
#pragma unroll
      for (int m = 0; m < 2; ++m)
#pragma unroll
        for (int n = 0; n < 8; ++n)
          s_[m][n] = __builtin_amdgcn_mfma_f32_16x16x32_bf16(qa[m][ks], kbr[n], s_[m][n], 0, 0, 0);
    }

    // ---- online softmax: defer-max (THR=8 in log2 units)
    float lmx[2][4];
#pragma unroll
    for (int m = 0; m < 2; ++m)
#pragma unroll
      for (int r = 0; r < 4; ++r) {
        float v = s_[m][0][r];
#pragma unroll
        for (int n = 1; n < 8; ++n) v = fmaxf(v, s_[m][n][r]);
        lmx[m][r] = v;
      }
    int need = 0;
#pragma unroll
    for (int m = 0; m < 2; ++m)
#pragma unroll
      for (int r = 0; r < 4; ++r)
        need |= (lmx[m][r] > mrun[m][r] + 8.0f) ? 1 : 0;
    if (__any(need)) {
#pragma unroll
      for (int m = 0; m < 2; ++m)
#pragma unroll
        for (int r = 0; r < 4; ++r) {
          float mx = fmaxf(lmx[m][r], mrun[m][r]);
          mx = fmaxf(mx, __shfl_xor(mx, 1));
          mx = fmaxf(mx, __shfl_xor(mx, 2));
          mx = fmaxf(mx, __shfl_xor(mx, 4));
          mx = fmaxf(mx, __shfl_xor(mx, 8));
          float sc = EXP2(mrun[m][r] - mx);
          mrun[m][r] = mx;
          lsum[m][r] *= sc;
#pragma unroll
          for (int nd = 0; nd < 4; ++nd) octx[m][nd][r] *= sc;
        }
    }

    // ---- hoist all V fragments (read once, used by both mm halves)
    s16x8 vbr[4][4];
#pragma unroll
    for (int ks = 0; ks < 4; ++ks)
#pragma unroll
      for (int nd = 0; nd < 4; ++nd)
        vbr[ks][nd] = *reinterpret_cast<const s16x8*>(
            Vs + (nd * 16 + lr) * 256 + ((ks * 64 + lg * 16) ^ ((lr & 7) << 4)));

    // ---- per-m-half: exp2 + conflict-free P writes, then PV
#pragma unroll
    for (int mm = 0; mm < 2; ++mm) {
#pragma unroll
      for (int r = 0; r < 4; ++r) {
        int rowbase = (lg * 4 + r) * 256;
        int mask = lg << 5;  // (row&12)<<3 with row=lg*4+r
#pragma unroll
        for (int n = 0; n < 8; ++n) {
          float p = EXP2(s_[mm][n][r] - mrun[mm][r]);
          lsum[mm][r] += p;
          *reinterpret_cast<unsigned short*>(
              Pw + rowbase + (((n * 16 + lr) * 2) ^ mask)) =
              (unsigned short)(fbits(p) >> 16);  // RTZ bf16
        }
      }
      // wave-private P; in-order DS pipe -> no barrier needed
#pragma unroll
      for (int ks = 0; ks < 4; ++ks) {
        s16x8 pa = *reinterpret_cast<const s16x8*>(
            Pw + lr * 256 + ((ks * 64 + lg * 16) ^ ((lr & 12) << 3)));
#pragma unroll
        for (int nd = 0; nd < 4; ++nd)
          octx[mm][nd] = __builtin_amdgcn_mfma_f32_16x16x32_bf16(pa, vbr[ks][nd], octx[mm][nd], 0, 0, 0);
      }
    }

    // ---- drain this iter's prefetch, then release buffers
    if (it < 15) {
      asm volatile("s_waitcnt vmcnt(0)" ::: "memory");
      __builtin_amdgcn_s_barrier();
      __builtin_amdgcn_sched_barrier(0);
      cur ^= 1;
    }
  }

  // ---- epilogue: cross-lane sum reduce, normalize, store bf16
#pragma unroll
  for (int m = 0; m < 2; ++m)
#pragma unroll
    for (int r = 0; r < 4; ++r) {
      float tot = lsum[m][r];
      tot += __shfl_xor(tot, 1);
      tot += __shfl_xor(tot, 2);
      tot += __shfl_xor(tot, 4);
      tot += __shfl_xor(tot, 8);
      float inv = 1.0f / tot;
      int qrow = qt * 128 + w * 32 + m * 16 + lg * 4 + r;
#pragma unroll
      for (int nd = 0; nd < 4; ++nd)
        ctx[(size_t)(b * 2048 + qrow) * 1024 + h * 64 + nd * 16 + lr] =
            f2bf(octx[m][nd][r] * inv);
    }
}

// ---------------------------------------------------------------------------
// Launch
// ---------------------------------------------------------------------------
extern "C" void kernel_launch(void* const* d_in, const int* in_sizes, int n_in,
                              void* d_out, int out_size, void* d_ws, size_t ws_size,
                              hipStream_t stream) {
  const float* hs  = (const float*)d_in[0];
  const float* kvs = (const float*)d_in[1];
  const float* wq  = (const float*)d_in[2];
  const float* wk  = (const float*)d_in[3];
  const float* wv  = (const float*)d_in[4];
  const float* wo  = (const float*)d_in[5];
  const float* nw  = (const float*)d_in[6];
  float* out = (float*)d_out;
  char* ws = (char*)d_ws;

  unsigned short* normed = (unsigned short*)(ws + (size_t)0);
  unsigned short* kvb    = (unsigned short*)(ws + ((size_t)8 << 20));
  unsigned short* wqT    = (unsigned short*)(ws + ((size_t)16 << 20));
  unsigned short* wkT    = (unsigned short*)(ws + ((size_t)18 << 20));
  unsigned short* wvT    = (unsigned short*)(ws + ((size_t)20 << 20));
  unsigned short* woT    = (unsigned short*)(ws + ((size_t)22 << 20));
  unsigned short* qb     = (unsigned short*)(ws + ((size_t)24 << 20));
  unsigned short* kb     = (unsigned short*)(ws + ((size_t)32 << 20));
  unsigned short* vTb    = (unsigned short*)(ws + ((size_t)40 << 20));
  unsigned short* ctxb   = (unsigned short*)(ws + ((size_t)48 << 20));

  k_transpose4<<<dim3(16, 16, 4), 256, 0, stream>>>(wq, wk, wv, wo, wqT, wkT, wvT, woT);
  k_rmsnorm<<<4096, 256, 0, stream>>>(hs, nw, normed);
  k_cast<<<1024, 256, 0, stream>>>(kvs, kvb, 1048576);

  k_gemm_qkv<<<dim3(8, 32, 3), 256, 0, stream>>>(normed, kvb, wqT, wkT, wvT, qb, kb, vTb);

  k_attn<<<512, 256, 0, stream>>>(qb, kb, vTb, ctxb);

  k_gemm_o<<<dim3(8, 32), 256, 0, stream>>>(ctxb, woT, out, hs);
}

// Round 8
// 140.694 us; speedup vs baseline: 1.7981x; 1.1964x over previous
//
#include <hip/hip_runtime.h>

// ---------------------------------------------------------------------------
// T5 cross-attention fused pipeline for MI355X (gfx950)  — round 8
// B=2, Q=KV=2048, D_MODEL=1024, H=16, D=64
// attn: swapped QK^T (P lane-local) + kv-permutation PV -> fully in-register
// P path (zero shuffles); V read as matched-permutation b64 pairs; P LDS gone.
// ---------------------------------------------------------------------------

typedef __attribute__((ext_vector_type(8))) short  s16x8;   // 8 bf16 (A/B frag)
typedef __attribute__((ext_vector_type(4))) float  f32x4;   // C/D frag
typedef __attribute__((ext_vector_type(4))) int    i32x4;

#define LOG2E 1.4426950408889634f
#define EXP2(x) __builtin_amdgcn_exp2f(x)

__device__ __forceinline__ unsigned short f2bf(float f) {
  unsigned int u = __builtin_bit_cast(unsigned int, f);
  return (unsigned short)((u + 0x7FFFu + ((u >> 16) & 1u)) >> 16);  // RNE
}

__device__ __forceinline__ unsigned cvtpk(float lo, float hi) {
  unsigned r;
  asm("v_cvt_pk_bf16_f32 %0, %1, %2" : "=v"(r) : "v"(lo), "v"(hi));
  return r;
}

__device__ __forceinline__ void gload16(const void* g, void* l) {
  __builtin_amdgcn_global_load_lds(
      (const __attribute__((address_space(1))) unsigned int*)g,
      (__attribute__((address_space(3))) unsigned int*)l, 16, 0, 0);
}

// ---------------------------------------------------------------------------
// Transpose-cast x4 in one dispatch: out[n][k] = bf16(in[k][n]), 1024x1024
// ---------------------------------------------------------------------------
__global__ __launch_bounds__(256) void k_transpose4(
    const float* __restrict__ a0, const float* __restrict__ a1,
    const float* __restrict__ a2, const float* __restrict__ a3,
    unsigned short* __restrict__ o0, unsigned short* __restrict__ o1,
    unsigned short* __restrict__ o2, unsigned short* __restrict__ o3) {
  int z = blockIdx.z;
  const float* in = (z == 0) ? a0 : (z == 1) ? a1 : (z == 2) ? a2 : a3;
  unsigned short* out = (z == 0) ? o0 : (z == 1) ? o1 : (z == 2) ? o2 : o3;
  __shared__ float tile[64][65];
  int t = threadIdx.x;
  int tx = t & 15, ty = t >> 4;
  int r0 = blockIdx.y * 64, c0 = blockIdx.x * 64;
#pragma unroll
  for (int p = 0; p < 4; ++p) {
    int r = p * 16 + ty;
    float4 v = *reinterpret_cast<const float4*>(in + (size_t)(r0 + r) * 1024 + c0 + tx * 4);
    tile[r][tx * 4 + 0] = v.x; tile[r][tx * 4 + 1] = v.y;
    tile[r][tx * 4 + 2] = v.z; tile[r][tx * 4 + 3] = v.w;
  }
  __syncthreads();
#pragma unroll
  for (int p = 0; p < 4; ++p) {
    int c = p * 16 + ty;
    unsigned int lo = (unsigned int)f2bf(tile[tx * 4 + 0][c]) |
                      ((unsigned int)f2bf(tile[tx * 4 + 1][c]) << 16);
    unsigned int hi = (unsigned int)f2bf(tile[tx * 4 + 2][c]) |
                      ((unsigned int)f2bf(tile[tx * 4 + 3][c]) << 16);
    uint2 pk2; pk2.x = lo; pk2.y = hi;
    *reinterpret_cast<uint2*>(out + (size_t)(c0 + c) * 1024 + r0 + tx * 4) = pk2;
  }
}

// ---------------------------------------------------------------------------
// RMSNorm + cast to bf16, scaled by log2(e) (feeds ONLY the Q projection ->
// QK^T scores land in the exp2 domain for free).
// ---------------------------------------------------------------------------
__global__ __launch_bounds__(256) void k_rmsnorm(
    const float* __restrict__ hs, const float* __restrict__ w,
    unsigned short* __restrict__ out) {
  int row = blockIdx.x, t = threadIdx.x;
  float4 v = *reinterpret_cast<const float4*>(hs + (size_t)row * 1024 + t * 4);
  float s = v.x * v.x + v.y * v.y + v.z * v.z + v.w * v.w;
#pragma unroll
  for (int m = 1; m < 64; m <<= 1) s += __shfl_xor(s, m);
  __shared__ float ps[4];
  if ((t & 63) == 0) ps[t >> 6] = s;
  __syncthreads();
  float tot = ps[0] + ps[1] + ps[2] + ps[3];
  float sc = rsqrtf(tot * (1.0f / 1024.0f) + 1e-6f) * LOG2E;
  float4 wv = *reinterpret_cast<const float4*>(w + t * 4);
  unsigned int lo = (unsigned int)f2bf(v.x * sc * wv.x) |
                    ((unsigned int)f2bf(v.y * sc * wv.y) << 16);
  unsigned int hi = (unsigned int)f2bf(v.z * sc * wv.z) |
                    ((unsigned int)f2bf(v.w * sc * wv.w) << 16);
  uint2 pk2; pk2.x = lo; pk2.y = hi;
  *reinterpret_cast<uint2*>(out + (size_t)row * 1024 + t * 4) = pk2;
}

// ---------------------------------------------------------------------------
// Plain f32 -> bf16 cast
// ---------------------------------------------------------------------------
__global__ __launch_bounds__(256) void k_cast(
    const float* __restrict__ in, unsigned short* __restrict__ out, int n4) {
  int i = blockIdx.x * 256 + threadIdx.x;
  int stride = gridDim.x * 256;
  for (; i < n4; i += stride) {
    float4 v = *reinterpret_cast<const float4*>(in + (size_t)i * 4);
    unsigned int lo = (unsigned int)f2bf(v.x) | ((unsigned int)f2bf(v.y) << 16);
    unsigned int hi = (unsigned int)f2bf(v.z) | ((unsigned int)f2bf(v.w) << 16);
    uint2 pk2; pk2.x = lo; pk2.y = hi;
    *reinterpret_cast<uint2*>(out + (size_t)i * 4) = pk2;
  }
}

// ---------------------------------------------------------------------------
// GEMM body: C[M,N] = A[M,K] * Bt[N,K]^T (M=4096, N=1024, K=1024, bf16 in)
// 128x128 tile, BK=64, double-buffered LDS, 2-phase prefetch.
// mode 0: bf16 out; mode 1: bf16 out transposed to vT [b][h][d][2048];
// mode 2: f32 out + residual
// ---------------------------------------------------------------------------
__device__ __forceinline__ void gemm_body(
    const unsigned short* __restrict__ A, const unsigned short* __restrict__ Bt,
    void* __restrict__ Cout, const float* __restrict__ resid, int mode) {
  __shared__ __align__(16) char sm[65536];
  int t = threadIdx.x;
  int bn = blockIdx.x, bm = blockIdx.y;
  int m0 = bm * 128, n0 = bn * 128;
  int lane = t & 63, w = t >> 6, lr = lane & 15, lg = lane >> 4;
  int wr = w >> 1, wc = w & 1;

  f32x4 acc[4][4] = {};

  const char* aA = (const char*)A + ((size_t)(m0 + (t >> 3)) * 1024 + (t & 7) * 8) * 2;
  const char* aB = (const char*)Bt + ((size_t)(n0 + (t >> 3)) * 1024 + (t & 7) * 8) * 2;

  auto stage = [&](int buf, int kt) {
    int koff = kt * 128;  // bytes into the K dimension
    char* As = sm + buf * 16384;
    char* Bs = sm + 32768 + buf * 16384;
#pragma unroll
    for (int c = 0; c < 4; ++c) {
      gload16(aA + (size_t)c * 65536 + koff, As + c * 4096 + t * 16);
      gload16(aB + (size_t)c * 65536 + koff, Bs + c * 4096 + t * 16);
    }
  };

  stage(0, 0);
  __syncthreads();
  int cur = 0;
  for (int kt = 0; kt < 16; ++kt) {
    if (kt < 15) stage(cur ^ 1, kt + 1);
    const char* As = sm + cur * 16384;
    const char* Bs = sm + 32768 + cur * 16384;
    s16x8 af[2][4], bfr[2][4];
#pragma unroll
    for (int ks = 0; ks < 2; ++ks) {
#pragma unroll
      for (int m = 0; m < 4; ++m)
        af[ks][m] = *reinterpret_cast<const s16x8*>(
            As + (wr * 64 + m * 16 + lr) * 128 + ks * 64 + lg * 16);
#pragma unroll
      for (int n = 0; n < 4; ++n)
        bfr[ks][n] = *reinterpret_cast<const s16x8*>(
            Bs + (wc * 64 + n * 16 + lr) * 128 + ks * 64 + lg * 16);
    }
#pragma unroll
    for (int ks = 0; ks < 2; ++ks)
#pragma unroll
      for (int m = 0; m < 4; ++m)
#pragma unroll
        for (int n = 0; n < 4; ++n)
          acc[m][n] = __builtin_amdgcn_mfma_f32_16x16x32_bf16(af[ks][m], bfr[ks][n], acc[m][n], 0, 0, 0);
    __syncthreads();
    cur ^= 1;
  }

#pragma unroll
  for (int m = 0; m < 4; ++m)
#pragma unroll
    for (int n = 0; n < 4; ++n) {
      int colg = n0 + wc * 64 + n * 16 + lr;
      int rowb = m0 + wr * 64 + m * 16 + lg * 4;
      if (mode == 0) {
        unsigned short* C = (unsigned short*)Cout;
#pragma unroll
        for (int r = 0; r < 4; ++r)
          C[(size_t)(rowb + r) * 1024 + colg] = f2bf(acc[m][n][r]);
      } else if (mode == 1) {
        int h = colg >> 6, d = colg & 63;
        int b = rowb >> 11, kv = rowb & 2047;
        unsigned short* C = (unsigned short*)Cout +
            ((size_t)((b * 16 + h) * 64 + d) * 2048 + kv);
        unsigned int lo = (unsigned int)f2bf(acc[m][n][0]) |
                          ((unsigned int)f2bf(acc[m][n][1]) << 16);
        unsigned int hi = (unsigned int)f2bf(acc[m][n][2]) |
                          ((unsigned int)f2bf(acc[m][n][3]) << 16);
        uint2 pk2; pk2.x = lo; pk2.y = hi;
        *reinterpret_cast<uint2*>(C) = pk2;
      } else {
        float* C = (float*)Cout;
#pragma unroll
        for (int r = 0; r < 4; ++r) {
          size_t idx = (size_t)(rowb + r) * 1024 + colg;
          C[idx] = resid[idx] + acc[m][n][r];
        }
      }
    }
}

__global__ __launch_bounds__(256) void k_gemm_qkv(
    const unsigned short* __restrict__ normed, const unsigned short* __restrict__ kvb,
    const unsigned short* __restrict__ wqT, const unsigned short* __restrict__ wkT,
    const unsigned short* __restrict__ wvT,
    unsigned short* __restrict__ qb, unsigned short* __restrict__ kb,
    unsigned short* __restrict__ vTb) {
  int z = blockIdx.z;
  const unsigned short* A = (z == 0) ? normed : kvb;
  const unsigned short* B = (z == 0) ? wqT : (z == 1) ? wkT : wvT;
  void* C = (z == 0) ? (void*)qb : (z == 1) ? (void*)kb : (void*)vTb;
  gemm_body(A, B, C, nullptr, (z == 2) ? 1 : 0);
}

__global__ __launch_bounds__(256) void k_gemm_o(
    const unsigned short* __restrict__ ctxb, const unsigned short* __restrict__ woT,
    float* __restrict__ out, const float* __restrict__ hs) {
  gemm_body(ctxb, woT, (void*)out, hs, 2);
}

// ---------------------------------------------------------------------------
// Flash attention, round 8.
// Grid: 512 blocks 1D (XCD-clustered); block 256 = 4 waves; wave owns 32 q.
// LDS (64KB): Ks dbuf 2x16K | Vs dbuf 2x16K.  (P LDS eliminated.)
//
// Swapped QK^T: s2 = mfma(K_frag, Q_frag) -> lane holds P[q=lr][kv=n*16+lg*4+r]
// (one q-row per lane; softmax stats are lane scalars, cross-lg reduce via
// shfl_xor 16/32). PV uses the kv-permutation pi(k=lg*8+j) =
// (2ks+(j>>2))*16 + lg*4 + (j&3) applied to BOTH operands: A-frag = the
// lane's own cvt_pk pairs (zero shuffles), B-frag = V read as 2x b64 at the
// matching columns. Output octx layout identical to previous rounds.
// ---------------------------------------------------------------------------
__global__ __launch_bounds__(256) void k_attn(
    const unsigned short* __restrict__ q, const unsigned short* __restrict__ k,
    const unsigned short* __restrict__ vt, unsigned short* __restrict__ ctx) {
  __shared__ __align__(16) char sm[65536];
  // Ks0 @0, Ks1 @16K, Vs0 @32K, Vs1 @48K
  int t = threadIdx.x, w = t >> 6, lane = t & 63, lr = lane & 15, lg = lane >> 4;

  // XCD-aware decomposition: 64 consecutive-slot blocks per XCD = 4 heads
  int bid = blockIdx.x;
  int xcd = bid & 7, slot = bid >> 3;
  int bh = xcd * 4 + (slot >> 4);   // [0,32)
  int qt = slot & 15;               // [0,16)
  int b = bh >> 4, h = bh & 15;

  const char* qB = (const char*)q + ((size_t)(b * 2048 + qt * 128) * 1024 + h * 64) * 2;
  const char* kB = (const char*)k + ((size_t)(b * 2048) * 1024 + h * 64) * 2;
  const char* vB = (const char*)vt + (size_t)bh * 64 * 4096;

  // staging geometry (pre-unswizzled sources; dest is lane-linear)
  int krow = t >> 3;
  int kcb  = ((t & 7) * 16) ^ ((krow & 7) << 4);
  int vrow = t >> 4;
  int vcb  = ((t & 15) * 16) ^ ((vrow & 7) << 4);

  auto stageKV = [&](int buf, int it2) {
    char* Kd = sm + buf * 16384;
    char* Vd = sm + 32768 + buf * 16384;
    const char* kb2 = kB + (size_t)(it2 * 128) * 2048;
    const char* vb2 = vB + it2 * 256;
#pragma unroll
    for (int c = 0; c < 4; ++c) {
      gload16(kb2 + (size_t)(c * 32 + krow) * 2048 + kcb, Kd + c * 4096 + t * 16);
      gload16(vb2 + (size_t)(c * 16 + vrow) * 4096 + vcb, Vd + c * 4096 + t * 16);
    }
  };

  // ---- prologue: stage Q into Ks0, read frags, then prefetch tile 0
#pragma unroll
  for (int c = 0; c < 4; ++c)
    gload16(qB + (size_t)(c * 32 + krow) * 2048 + kcb, sm + c * 4096 + t * 16);
  __syncthreads();
  s16x8 qa[2][2];
#pragma unroll
  for (int mm = 0; mm < 2; ++mm)
#pragma unroll
    for (int ks = 0; ks < 2; ++ks) {
      int row = w * 32 + mm * 16 + lr;
      qa[mm][ks] = *reinterpret_cast<const s16x8*>(
          sm + row * 128 + ((ks * 64 + lg * 16) ^ ((lr & 7) << 4)));
    }
  __syncthreads();  // all q-frag reads done before staging overwrites Ks0
  stageKV(0, 0);
  asm volatile("s_waitcnt vmcnt(0)" ::: "memory");
  __builtin_amdgcn_s_barrier();
  __builtin_amdgcn_sched_barrier(0);

  f32x4 octx[2][4] = {};
  float mrun[2] = {-1e30f, -1e30f};
  float lsum[2] = {0.0f, 0.0f};

  int cur = 0;
  for (int it = 0; it < 16; ++it) {
    // ---- issue next tile's staging (completes under this iter's compute)
    if (it < 15) stageKV(cur ^ 1, it + 1);

    const char* Ks = sm + cur * 16384;
    const char* Vs = sm + 32768 + cur * 16384;

    // ---- S^T = K Q^T (swapped): lane holds S[q=lr][kv=n*16+lg*4+r], half mm
    f32x4 s2[2][8] = {};
#pragma unroll
    for (int ks = 0; ks < 2; ++ks) {
      s16x8 ka[8];
#pragma unroll
      for (int n = 0; n < 8; ++n)
        ka[n] = *reinterpret_cast<const s16x8*>(
            Ks + (n * 16 + lr) * 128 + ((ks * 64 + lg * 16) ^ ((lr & 7) << 4)));
#pragma unroll
      for (int mm = 0; mm < 2; ++mm)
#pragma unroll
        for (int n = 0; n < 8; ++n)
          s2[mm][n] = __builtin_amdgcn_mfma_f32_16x16x32_bf16(ka[n], qa[mm][ks], s2[mm][n], 0, 0, 0);
    }

    // ---- online softmax (per-lane row stats; reduce across lg groups)
    float m2[2];
#pragma unroll
    for (int mm = 0; mm < 2; ++mm) {
      float v = s2[mm][0][0];
#pragma unroll
      for (int n = 0; n < 8; ++n)
#pragma unroll
        for (int r = 0; r < 4; ++r) v = fmaxf(v, s2[mm][n][r]);
      v = fmaxf(v, __shfl_xor(v, 16));
      v = fmaxf(v, __shfl_xor(v, 32));
      m2[mm] = v;
    }
    int need = (m2[0] > mrun[0] + 8.0f) || (m2[1] > mrun[1] + 8.0f);
    if (__any(need)) {
#pragma unroll
      for (int mm = 0; mm < 2; ++mm) {
        float mx = fmaxf(mrun[mm], m2[mm]);
        float sc = EXP2(mrun[mm] - mx);
        mrun[mm] = mx;
        lsum[mm] *= sc;
#pragma unroll
        for (int r = 0; r < 4; ++r) {
          float scr = __shfl(sc, lg * 4 + r);
#pragma unroll
          for (int nd = 0; nd < 4; ++nd) octx[mm][nd][r] *= scr;
        }
      }
    }

    // ---- exp2 + in-register bf16 pack (lane-local; zero cross-lane moves)
    unsigned pk[2][8][2];
#pragma unroll
    for (int mm = 0; mm < 2; ++mm) {
      float a0 = 0.0f, a1 = 0.0f, a2 = 0.0f, a3 = 0.0f;
#pragma unroll
      for (int n = 0; n < 8; ++n) {
        float p0 = EXP2(s2[mm][n][0] - mrun[mm]);
        float p1 = EXP2(s2[mm][n][1] - mrun[mm]);
        float p2 = EXP2(s2[mm][n][2] - mrun[mm]);
        float p3 = EXP2(s2[mm][n][3] - mrun[mm]);
        a0 += p0; a1 += p1; a2 += p2; a3 += p3;
        pk[mm][n][0] = cvtpk(p0, p1);
        pk[mm][n][1] = cvtpk(p2, p3);
      }
      lsum[mm] += (a0 + a1) + (a2 + a3);
    }

    // ---- PV with permuted kv order (A = own pk regs; B = matching V cols)
#pragma unroll
    for (int ks = 0; ks < 4; ++ks) {
      s16x8 vb[4];
#pragma unroll
      for (int nd = 0; nd < 4; ++nd) {
        int row = nd * 16 + lr;
        int swz = (lr & 7) << 4;
        uint2 v1 = *reinterpret_cast<const uint2*>(
            Vs + row * 256 + ((ks * 64 + lg * 8) ^ swz));
        uint2 v2 = *reinterpret_cast<const uint2*>(
            Vs + row * 256 + ((ks * 64 + 32 + lg * 8) ^ swz));
        i32x4 vv; vv[0] = (int)v1.x; vv[1] = (int)v1.y;
        vv[2] = (int)v2.x; vv[3] = (int)v2.y;
        vb[nd] = __builtin_bit_cast(s16x8, vv);
      }
#pragma unroll
      for (int mm = 0; mm < 2; ++mm) {
        i32x4 pv;
        pv[0] = (int)pk[mm][2 * ks][0];     pv[1] = (int)pk[mm][2 * ks][1];
        pv[2] = (int)pk[mm][2 * ks + 1][0]; pv[3] = (int)pk[mm][2 * ks + 1][1];
        s16x8 pa = __builtin_bit_cast(s16x8, pv);
#pragma unroll
        for (int nd = 0; nd < 4; ++nd)
          octx[mm][nd] = __builtin_amdgcn_mfma_f32_16x16x32_bf16(pa, vb[nd], octx[mm][nd], 0, 0, 0);
      }
    }

    // ---- drain this iter's prefetch, then release buffers
    if (it < 15) {
      asm volatile("s_waitcnt vmcnt(0)" ::: "memory");
      __builtin_amdgcn_s_barrier();
      __builtin_amdgcn_sched_barrier(0);
      cur ^= 1;
    }
  }

  // ---- epilogue: reduce lsum across lg, normalize, store bf16
#pragma unroll
  for (int mm = 0; mm < 2; ++mm) {
    float tot = lsum[mm];
    tot += __shfl_xor(tot, 16);
    tot += __shfl_xor(tot, 32);
    float inv = 1.0f / tot;
#pragma unroll
    for (int r = 0; r < 4; ++r) {
      float invr = __shfl(inv, lg * 4 + r);
      int qrow = qt * 128 + w * 32 + mm * 16 + lg * 4 + r;
#pragma unroll
      for (int nd = 0; nd < 4; ++nd)
        ctx[(size_t)(b * 2048 + qrow) * 1024 + h * 64 + nd * 16 + lr] =
            f2bf(octx[mm][nd][r] * invr);
    }
  }
}

// ---------------------------------------------------------------------------
// Launch
// ---------------------------------------------------------------------------
extern "C" void kernel_launch(void* const* d_in, const int* in_sizes, int n_in,
                              void* d_out, int out_size, void* d_ws, size_t ws_size,
                              hipStream_t stream) {
  const float* hs  = (const float*)d_in[0];
  const float* kvs = (const float*)d_in[1];
  const float* wq  = (const float*)d_in[2];
  const float* wk  = (const float*)d_in[3];
  const float* wv  = (const float*)d_in[4];
  const float* wo  = (const float*)d_in[5];
  const float* nw  = (const float*)d_in[6];
  float* out = (float*)d_out;
  char* ws = (char*)d_ws;

  unsigned short* normed = (unsigned short*)(ws + (size_t)0);
  unsigned short* kvb    = (unsigned short*)(ws + ((size_t)8 << 20));
  unsigned short* wqT    = (unsigned short*)(ws + ((size_t)16 << 20));
  unsigned short* wkT    = (unsigned short*)(ws + ((size_t)18 << 20));
  unsigned short* wvT    = (unsigned short*)(ws + ((size_t)20 << 20));
  unsigned short* woT    = (unsigned short*)(ws + ((size_t)22 << 20));
  unsigned short* qb     = (unsigned short*)(ws + ((size_t)24 << 20));
  unsigned short* kb     = (unsigned short*)(ws + ((size_t)32 << 20));
  unsigned short* vTb    = (unsigned short*)(ws + ((size_t)40 << 20));
  unsigned short* ctxb   = (unsigned short*)(ws + ((size_t)48 << 20));

  k_transpose4<<<dim3(16, 16, 4), 256, 0, stream>>>(wq, wk, wv, wo, wqT, wkT, wvT, woT);
  k_rmsnorm<<<4096, 256, 0, stream>>>(hs, nw, normed);
  k_cast<<<1024, 256, 0, stream>>>(kvs, kvb, 1048576);

  k_gemm_qkv<<<dim3(8, 32, 3), 256, 0, stream>>>(normed, kvb, wqT, wkT, wvT, qb, kb, vTb);

  k_attn<<<512, 256, 0, stream>>>(qb, kb, vTb, ctxb);

  k_gemm_o<<<dim3(8, 32), 256, 0, stream>>>(ctxb, woT, out, hs);
}